// Round 8
// baseline (134.482 us; speedup 1.0000x reference)
//
#include <hip/hip_runtime.h>

// DCNv2, fp32 in/out, fused MFMA path, cin-split across wave pairs for TLP.
// (1) x NCHW -> xT bf16 NHWC,
// (2) prep: wd A-frags + wo split (hi/lo) A-frags,
// (3) fused: block = 4 waves = 2 px-tiles x 2 kc-halves. Each wave: 16 px,
//     32 cin (its kc half), 64 cout. Offset-conv partials summed in LDS (fp32),
//     one barrier, deform phase, then cross-kc accumulator reduce in LDS.
// B-frag: n=lane&15, k=(lane>>4)*8+j (K=32).  D: col=lane&15, row=(lane>>4)*4+reg.
// ws: xT 8388608 B | wdA 73728 B | woAhi 36864 B | woAlo 36864 B

#define BATCH 4
#define CIN   64
#define COUT  64
#define HH    128
#define WW    128
#define HWPIX (HH*WW)

typedef __attribute__((ext_vector_type(8))) short short8;   // 8 bf16 (4 VGPRs)
typedef __attribute__((ext_vector_type(4))) float floatx4;  // MFMA C/D

__device__ __forceinline__ unsigned short f2bf(float f) {   // RNE f32->bf16
  unsigned int u = __float_as_uint(f);
  unsigned int r = u + 0x7fffu + ((u >> 16) & 1u);
  return (unsigned short)(r >> 16);
}
__device__ __forceinline__ float bf2f(unsigned short h) { return __uint_as_float(((unsigned int)h) << 16); }
__device__ __forceinline__ float lo16f(unsigned int u) { return __uint_as_float(u << 16); }
__device__ __forceinline__ float hi16f(unsigned int u) { return __uint_as_float(u & 0xffff0000u); }

__device__ __forceinline__ unsigned int bilin2(unsigned int u00, unsigned int u01,
                                               unsigned int u10, unsigned int u11,
                                               float w00, float w01, float w10, float w11) {
  float lo = w00 * lo16f(u00) + w01 * lo16f(u01) + w10 * lo16f(u10) + w11 * lo16f(u11);
  float hi = w00 * hi16f(u00) + w01 * hi16f(u01) + w10 * hi16f(u10) + w11 * hi16f(u11);
  return (unsigned int)f2bf(lo) | ((unsigned int)f2bf(hi) << 16);
}

// x fp32 NCHW -> xT bf16 [b][px][cin]
__global__ __launch_bounds__(256) void transpose_x_kernel(const float* __restrict__ x,
                                                          unsigned short* __restrict__ xT) {
  __shared__ float tile[32][33];   // [c_local][p_local]
  int b = blockIdx.z, p0 = blockIdx.x * 32, c0 = blockIdx.y * 32;
  int tx = threadIdx.x, ty = threadIdx.y;        // (32,8)
  const float* xb = x + (size_t)b * CIN * HWPIX;
  unsigned short* xTb = xT + (size_t)b * HWPIX * CIN;
#pragma unroll
  for (int i = 0; i < 4; i++)
    tile[ty + i * 8][tx] = xb[(size_t)(c0 + ty + i * 8) * HWPIX + p0 + tx];
  __syncthreads();
  int wid = ty * 32 + tx;          // 0..255 = 32 rows x 8 cin-quads
  int row = wid >> 3, q = wid & 7;
  ushort4 v = make_ushort4(f2bf(tile[q * 4 + 0][row]), f2bf(tile[q * 4 + 1][row]),
                           f2bf(tile[q * 4 + 2][row]), f2bf(tile[q * 4 + 3][row]));
  *(ushort4*)&xTb[(size_t)(p0 + row) * CIN + c0 + q * 4] = v;
}

// wdA[kk][kc2][ct4][lane][j] bf16 (36864 entries);
// woAhi/lo[kk][kc2][ct2][lane][j] bf16 (M=32 rows, rows>=18 zero; 18432 each)
__global__ __launch_bounds__(256) void prep_weights_kernel(const float* __restrict__ wo,
                                                           const float* __restrict__ wd,
                                                           unsigned short* __restrict__ wdA,
                                                           unsigned short* __restrict__ woAhi,
                                                           unsigned short* __restrict__ woAlo) {
  int t = blockIdx.x * 256 + threadIdx.x;
  if (t < 36864) {
    int j = t & 7, lane = (t >> 3) & 63, ct = (t >> 9) & 3, kc = (t >> 11) & 1, kk = t >> 12;
    int cout = ct * 16 + (lane & 15);
    int cin  = kc * 32 + (lane >> 4) * 8 + j;
    wdA[t] = f2bf(wd[(size_t)(cout * CIN + cin) * 9 + kk]);
  }
  int t2 = t - 36864;
  if (t2 >= 0 && t2 < 18432) {
    int j = t2 & 7, lane = (t2 >> 3) & 63, ct = (t2 >> 9) & 1, kc = (t2 >> 10) & 1, kk = t2 >> 11;
    int cout = ct * 16 + (lane & 15);          // conv channel 0..31 (valid < 18)
    int cin  = kc * 32 + (lane >> 4) * 8 + j;
    float v = (cout < 18) ? wo[(size_t)(cout * CIN + cin) * 9 + kk] : 0.f;
    unsigned short h = f2bf(v);
    woAhi[t2] = h;
    woAlo[t2] = f2bf(v - bf2f(h));
  }
}

// Fused offset-conv + deform, cin-split. Block = 4 waves (2 tiles x 2 kc), 32 px.
__global__ __launch_bounds__(256) void fused_dcn_kernel(const unsigned short* __restrict__ xT,
                                                        const unsigned short* __restrict__ wdA,
                                                        const unsigned short* __restrict__ woAhi,
                                                        const unsigned short* __restrict__ woAlo,
                                                        float* __restrict__ out) {
  __shared__ float shmem[2048];        // 8 KB: offsP (1152 f) then redL (2048 f)
  float* offsP = shmem;                // [wave][18][16] partial offsets
  float* redL  = shmem;                // [tile][ct][rr][lane] after re-barrier

  int tid = threadIdx.x;
  int lane = tid & 63, w = tid >> 6;
  int t = w >> 1, kc = w & 1;          // px-tile, cin-half
  int hw = blockIdx.x;                 // 2048 blocks
  int bid = (hw & 7) * 256 + (hw >> 3);  // XCD-contiguous bands (64 y-rows each)
  int b = bid >> 9, r = bid & 511, y = r >> 2, x0 = (r & 3) << 5;

  int pxl = lane & 15, kq = lane >> 4;
  int px  = x0 + t * 16 + pxl;
  int klo = kc * 32 + kq * 8;          // cin offset of this lane's 8-wide k-slice
  int rowb = kq * 4;                   // D-frag row base

  const unsigned short* xTb = xT + (size_t)b * HWPIX * CIN;
  const short8 zero8 = {0, 0, 0, 0, 0, 0, 0, 0};

  // ---------- phase A: offset conv partial (this kc half) ----------
  {
    floatx4 oacc[2];
    oacc[0] = (floatx4){0.f, 0.f, 0.f, 0.f};
    oacc[1] = (floatx4){0.f, 0.f, 0.f, 0.f};
#pragma unroll
    for (int kk = 0; kk < 9; kk++) {
      int ys = y - 1 + kk / 3;
      int xs = px - 1 + kk % 3;
      short8 b0 = zero8;
      if (ys >= 0 && ys < HH && xs >= 0 && xs < WW)
        b0 = *(const short8*)(xTb + (size_t)(ys * WW + xs) * CIN + klo);
      const short8* Ah = (const short8*)(woAhi + (size_t)kk * 2048 + kc * 1024);
      const short8* Al = (const short8*)(woAlo + (size_t)kk * 2048 + kc * 1024);
#pragma unroll
      for (int ct = 0; ct < 2; ct++) {
        oacc[ct] = __builtin_amdgcn_mfma_f32_16x16x32_bf16(Ah[ct * 64 + lane], b0, oacc[ct], 0, 0, 0);
        oacc[ct] = __builtin_amdgcn_mfma_f32_16x16x32_bf16(Al[ct * 64 + lane], b0, oacc[ct], 0, 0, 0);
      }
    }
#pragma unroll
    for (int ct = 0; ct < 2; ct++)
#pragma unroll
      for (int rr = 0; rr < 4; rr++) {
        int row = ct * 16 + rowb + rr;
        if (row < 18) offsP[(w * 18 + row) * 16 + pxl] = oacc[ct][rr];
      }
  }
  __syncthreads();

  // ---------- phase B: deform sample + contraction (this kc half) ----------
  floatx4 acc[4];
#pragma unroll
  for (int ct = 0; ct < 4; ct++) acc[ct] = (floatx4){0.f, 0.f, 0.f, 0.f};

#pragma unroll
  for (int kk = 0; kk < 9; kk++) {
    float dy = offsP[((2 * t) * 18 + 2 * kk) * 16 + pxl] +
               offsP[((2 * t + 1) * 18 + 2 * kk) * 16 + pxl];
    float dx = offsP[((2 * t) * 18 + 2 * kk + 1) * 16 + pxl] +
               offsP[((2 * t + 1) * 18 + 2 * kk + 1) * 16 + pxl];
    float ysf = (float)(y - 1 + kk / 3) + dy;
    float xsf = (float)(px - 1 + kk % 3) + dx;
    float y0f = floorf(ysf), x0f = floorf(xsf);
    float wy = ysf - y0f, wx = xsf - x0f;
    int iy0 = (int)y0f, ix0 = (int)x0f;
    int iy1 = iy0 + 1, ix1 = ix0 + 1;
    float w00 = (1.f - wy) * (1.f - wx), w01 = (1.f - wy) * wx;
    float w10 = wy * (1.f - wx), w11 = wy * wx;
    bool vy0 = (iy0 >= 0) && (iy0 < HH), vy1 = (iy1 >= 0) && (iy1 < HH);
    bool vx0 = (ix0 >= 0) && (ix0 < WW), vx1 = (ix1 >= 0) && (ix1 < WW);
    if (!(vy0 && vx0)) w00 = 0.f;
    if (!(vy0 && vx1)) w01 = 0.f;
    if (!(vy1 && vx0)) w10 = 0.f;
    if (!(vy1 && vx1)) w11 = 0.f;
    int cy0 = min(max(iy0, 0), HH - 1), cy1 = min(max(iy1, 0), HH - 1);
    int cx0 = min(max(ix0, 0), WW - 1), cx1 = min(max(ix1, 0), WW - 1);
    uint4 c00 = *(const uint4*)(xTb + (size_t)(cy0 * WW + cx0) * CIN + klo);
    uint4 c01 = *(const uint4*)(xTb + (size_t)(cy0 * WW + cx1) * CIN + klo);
    uint4 c10 = *(const uint4*)(xTb + (size_t)(cy1 * WW + cx0) * CIN + klo);
    uint4 c11 = *(const uint4*)(xTb + (size_t)(cy1 * WW + cx1) * CIN + klo);
    uint4 u;
    u.x = bilin2(c00.x, c01.x, c10.x, c11.x, w00, w01, w10, w11);
    u.y = bilin2(c00.y, c01.y, c10.y, c11.y, w00, w01, w10, w11);
    u.z = bilin2(c00.z, c01.z, c10.z, c11.z, w00, w01, w10, w11);
    u.w = bilin2(c00.w, c01.w, c10.w, c11.w, w00, w01, w10, w11);
    short8 bv = *(short8*)&u;
    const short8* Ap = (const short8*)(wdA + (size_t)kk * 4096 + kc * 2048);
#pragma unroll
    for (int ct = 0; ct < 4; ct++)
      acc[ct] = __builtin_amdgcn_mfma_f32_16x16x32_bf16(Ap[ct * 64 + lane], bv, acc[ct], 0, 0, 0);
  }

  // ---------- cross-kc reduce + store ----------
  __syncthreads();                     // offsP dead; reuse shmem as redL
  if (kc == 1) {
#pragma unroll
    for (int ct = 0; ct < 4; ct++)
#pragma unroll
      for (int rr = 0; rr < 4; rr++)
        redL[((t * 4 + ct) * 4 + rr) * 64 + lane] = acc[ct][rr];
  }
  __syncthreads();
  if (kc == 0) {
    float* outb = out + (size_t)b * COUT * HWPIX + y * WW + px;
#pragma unroll
    for (int ct = 0; ct < 4; ct++)
#pragma unroll
      for (int rr = 0; rr < 4; rr++) {
        float v = acc[ct][rr] + redL[((t * 4 + ct) * 4 + rr) * 64 + lane];
        outb[(size_t)(ct * 16 + rowb + rr) * HWPIX] = v;
      }
  }
}

extern "C" void kernel_launch(void* const* d_in, const int* in_sizes, int n_in,
                              void* d_out, int out_size, void* d_ws, size_t ws_size,
                              hipStream_t stream) {
  const float* x  = (const float*)d_in[0];
  const float* wo = (const float*)d_in[1];
  const float* wd = (const float*)d_in[2];
  float* out = (float*)d_out;

  char* wsb = (char*)d_ws;
  unsigned short* xT    = (unsigned short*)wsb;                      // 8,388,608 B
  unsigned short* wdA   = (unsigned short*)(wsb + 8388608);          // 73,728 B
  unsigned short* woAhi = (unsigned short*)(wsb + 8388608 + 73728);  // 36,864 B
  unsigned short* woAlo = (unsigned short*)(wsb + 8388608 + 110592); // 36,864 B

  transpose_x_kernel<<<dim3(HWPIX / 32, CIN / 32, BATCH), dim3(32, 8, 1), 0, stream>>>(x, xT);
  prep_weights_kernel<<<dim3(216), dim3(256), 0, stream>>>(wo, wd, wdA, woAhi, woAlo);
  fused_dcn_kernel<<<dim3(BATCH * HWPIX / 32), dim3(256), 0, stream>>>(xT, wdA, woAhi, woAlo, out);
}